// Round 4
// baseline (114.352 us; speedup 1.0000x reference)
//
#include <hip/hip_runtime.h>
#include <hip/hip_fp16.h>

#define D_MODEL 128
#define NB 4
#define NN 512

typedef _Float16 f16;
typedef _Float16 f16x8 __attribute__((ext_vector_type(8)));
typedef float f32x4 __attribute__((ext_vector_type(4)));

// ---------------------------------------------------------------------------
// Kernel 1: Hi = x @ W1[:128] + b1, Hj = x @ W1[128:]  (fp16), plus W2 prepack
// into mfma_f32_16x16x32_f16 B-fragment layout.
// blocks 0..127: 16 rows each of Hi/Hj.  block 128: W2 prepack.
// ---------------------------------------------------------------------------
__global__ __launch_bounds__(256) void prep_kernel(
    const float* __restrict__ x,    // [B*N,128]
    const float* __restrict__ W1,   // [256,128]
    const float* __restrict__ b1,   // [128]
    const float* __restrict__ W2,   // [128,64]
    f16* __restrict__ Hi, f16* __restrict__ Hj, f16* __restrict__ W2p)
{
    const int blk = blockIdx.x;
    const int t = threadIdx.x;
    if (blk < 128) {
        const int r0 = blk * 16;                 // global row (b*N+n)
        __shared__ float xs[16][128];
        for (int idx = t; idx < 16 * 128; idx += 256)
            xs[idx >> 7][idx & 127] = x[(size_t)r0 * 128 + idx];
        __syncthreads();

        const int isJ = t >> 7;                  // 0 -> Hi, 1 -> Hj
        const int k = t & 127;
        const float* wcol = W1 + (isJ ? 128 * 128 : 0) + k;
        float acc[16];
        #pragma unroll
        for (int r = 0; r < 16; r++) acc[r] = 0.f;
        for (int d = 0; d < 128; d++) {
            float w = wcol[d * 128];
            #pragma unroll
            for (int r = 0; r < 16; r++) acc[r] = fmaf(xs[r][d], w, acc[r]);
        }
        const float bb = isJ ? 0.f : b1[k];
        f16* dst = isJ ? Hj : Hi;
        #pragma unroll
        for (int r = 0; r < 16; r++)
            dst[(size_t)(r0 + r) * 128 + k] = (f16)(acc[r] + bb);
    } else {
        // W2 prepack: W2p[((kt*4+nt)*64 + lane)*8 + j] = W2[kt*32+8*(lane>>4)+j][nt*16+(lane&15)]
        for (int slot = t; slot < 16 * 64; slot += 256) {
            const int lane = slot & 63;
            const int fidx = slot >> 6;          // kt*4+nt
            const int kt = fidx >> 2, nt = fidx & 3;
            const int krow = kt * 32 + 8 * (lane >> 4);
            const int col = nt * 16 + (lane & 15);
            #pragma unroll
            for (int j = 0; j < 8; j++)
                W2p[(size_t)slot * 8 + j] = (f16)W2[(krow + j) * 64 + col];
        }
    }
}

// ---------------------------------------------------------------------------
// Kernel 2: per wave: 16 j's x 32 i's.  A = relu(Hi[i]+Hj[j]) built in regs,
// 16x mfma_f32_16x16x32_f16 per i (4 ktiles x 4 ntiles), fused epilogue.
// ---------------------------------------------------------------------------
__global__ __launch_bounds__(256) void pair_kernel(
    const f16* __restrict__ Hi, const f16* __restrict__ Hj,
    const f16* __restrict__ W2p,
    const float* __restrict__ b2, const float* __restrict__ W3,
    const float* __restrict__ b3p, float* __restrict__ out)
{
    const int lane = threadIdx.x & 63;
    const int wave = threadIdx.x >> 6;
    const int bid = blockIdx.x;                  // 4(b) * 16(ic) * 8(jg4)
    const int jg4 = bid & 7;
    const int ic  = (bid >> 3) & 15;
    const int b   = bid >> 7;
    const int j0 = (jg4 * 4 + wave) * 16;
    const int i0 = ic * 32;

    const int lrow = lane & 15;
    const int lgrp = lane >> 4;

    // W2 fragments (held in regs for the whole block)
    f16x8 w2f[4][4];
    #pragma unroll
    for (int kt = 0; kt < 4; kt++)
        #pragma unroll
        for (int nt = 0; nt < 4; nt++)
            w2f[kt][nt] = *(const f16x8*)(W2p + (size_t)((kt * 4 + nt) * 64 + lane) * 8);

    // Hj fragments for this wave's 16 j's (A-operand layout: row=lrow, k=8*lgrp+j)
    const f16* hjbase = Hj + (size_t)(b * NN + j0 + lrow) * 128 + 8 * lgrp;
    f16x8 hjf[4];
    #pragma unroll
    for (int kt = 0; kt < 4; kt++)
        hjf[kt] = *(const f16x8*)(hjbase + kt * 32);

    float b2v[4], w3v[4];
    #pragma unroll
    for (int nt = 0; nt < 4; nt++) {
        b2v[nt] = b2[nt * 16 + lrow];
        w3v[nt] = W3[nt * 16 + lrow];
    }
    const float b3 = b3p[0];

    const f16* hibase = Hi + (size_t)(b * NN + i0) * 128 + 8 * lgrp;
    float* obase = out + ((size_t)b * NN + i0) * NN + j0;

    const f16x8 zero8 = (f16x8)(f16)0;

    #pragma unroll 2
    for (int ii = 0; ii < 32; ii++) {
        f16x8 hif[4];
        #pragma unroll
        for (int kt = 0; kt < 4; kt++)
            hif[kt] = *(const f16x8*)(hibase + ii * 128 + kt * 32);

        f32x4 accD[4];
        #pragma unroll
        for (int nt = 0; nt < 4; nt++) accD[nt] = (f32x4)(0.0f);

        #pragma unroll
        for (int kt = 0; kt < 4; kt++) {
            f16x8 s = hif[kt] + hjf[kt];                     // v_pk_add_f16 x4
            s = __builtin_elementwise_max(s, zero8);         // v_pk_max_f16 x4
            #pragma unroll
            for (int nt = 0; nt < 4; nt++)
                accD[nt] = __builtin_amdgcn_mfma_f32_16x16x32_f16(s, w2f[kt][nt], accD[nt], 0, 0, 0);
        }

        // epilogue: h2 = relu(D + b2); partial = h2 * W3; reduce over 16 lanes
        float acc[4] = {0.f, 0.f, 0.f, 0.f};
        #pragma unroll
        for (int nt = 0; nt < 4; nt++) {
            #pragma unroll
            for (int r = 0; r < 4; r++) {
                float h = fmaxf(accD[nt][r] + b2v[nt], 0.f);
                acc[r] = fmaf(h, w3v[nt], acc[r]);
            }
        }
        #pragma unroll
        for (int r = 0; r < 4; r++) {
            #pragma unroll
            for (int m = 1; m < 16; m <<= 1)
                acc[r] += __shfl_xor(acc[r], m, 64);
        }
        if (lrow == 0) {
            float4 o;
            float lg0 = acc[0] + b3, lg1 = acc[1] + b3, lg2 = acc[2] + b3, lg3 = acc[3] + b3;
            o.x = 1.f / (1.f + __expf(-lg0));
            o.y = 1.f / (1.f + __expf(-lg1));
            o.z = 1.f / (1.f + __expf(-lg2));
            o.w = 1.f / (1.f + __expf(-lg3));
            *(float4*)(obase + (size_t)ii * NN + lgrp * 4) = o;
        }
    }
}

extern "C" void kernel_launch(void* const* d_in, const int* in_sizes, int n_in,
                              void* d_out, int out_size, void* d_ws, size_t ws_size,
                              hipStream_t stream) {
    const float* x  = (const float*)d_in[0];   // [4,512,128]
    const float* W1 = (const float*)d_in[1];   // [256,128]
    const float* b1 = (const float*)d_in[2];   // [128]
    const float* W2 = (const float*)d_in[3];   // [128,64]
    const float* b2 = (const float*)d_in[4];   // [64]
    const float* W3 = (const float*)d_in[5];   // [64,1]
    const float* b3 = (const float*)d_in[6];   // [1]
    float* out = (float*)d_out;                // [4,512,512]

    f16* Hi  = (f16*)d_ws;                     // 262144 halves
    f16* Hj  = Hi + (size_t)NB * NN * 128;     // 262144 halves
    f16* W2p = Hj + (size_t)NB * NN * 128;     // 8192 halves

    prep_kernel<<<129, 256, 0, stream>>>(x, W1, b1, W2, Hi, Hj, W2p);
    pair_kernel<<<512, 256, 0, stream>>>(Hi, Hj, W2p, b2, W3, b3, out);
}